// Round 10
// baseline (183.790 us; speedup 1.0000x reference)
//
#include <hip/hip_runtime.h>

// B=4, H=W=128, D=64, NH=2, hd=32, 9 taps. All inputs fp32; compute fp16 MFMA.
// R10: L2-direct weights, zero barriers. All weight fragments read straight
// from repacked global wf (1 KB coalesced per fragment, L2/L3-resident) —
// no global_load_lds staging, no vmcnt-drain barriers, no weight LDS.
// attn LDS shrinks to wave-private ff1 scratch (38 KB) -> 2 blocks/CU,
// 4 waves/SIMD (lb(512,4)). Convs barrier-free, LDS-free, same grid.
// Activations stay octet-plane [oct][px][8] (R8). One-pass online softmax (R6).

typedef _Float16 half8 __attribute__((ext_vector_type(8)));
typedef float f32x4 __attribute__((ext_vector_type(4)));

#define PLANE 524288  // 65536 pixels x 8 halves per plane

__device__ __forceinline__ f32x4 mfma16(half8 a, half8 b, f32x4 c) {
  return __builtin_amdgcn_mfma_f32_16x16x32_f16(a, b, c, 0, 0, 0);
}
__device__ __forceinline__ half8 ldfrag(const _Float16* p) { return *(const half8*)p; }
__device__ __forceinline__ half8 zfrag() { half8 z = {}; return z; }

// ---------------- prep: x -> fp16 octet planes + weight repack -------------
// blocks [0,2048): cvt, thread t -> px = b*32 + t/8, oct = t%8 (coalesced).
// blocks [2048,2944): weight repack into fragment layouts.
//   AQ  [mb4][kb2]      @ 0       AK  [t9][cb4][kb2]  @ 4096
//   BV  [t9][kb2][nb4]  @ 40960   B1  [kb2][nb4]      @ 77824
//   BF2 [t9][kb2][nb8]  @ 81920   BF3 [t9][kb4][nb4]  @ 155648  (229376 total)
__global__ __launch_bounds__(256) void prep(
    const float* __restrict__ x, const float* __restrict__ Kp,
    const float* __restrict__ Vp, const float* __restrict__ Qp,
    const float* __restrict__ W1, const float* __restrict__ F2,
    const float* __restrict__ F3, _Float16* __restrict__ xh,
    _Float16* __restrict__ out) {
  if (blockIdx.x < 2048) {
    const int t = threadIdx.x;
    const int px = blockIdx.x * 32 + (t >> 3);
    const int oct = t & 7;
    const float4* s = (const float4*)(x + (size_t)px * 64 + oct * 8);
    float4 a = s[0], b = s[1];
    half8 h = { (_Float16)a.x, (_Float16)a.y, (_Float16)a.z, (_Float16)a.w,
                (_Float16)b.x, (_Float16)b.y, (_Float16)b.z, (_Float16)b.w };
    *(half8*)(xh + (size_t)oct * PLANE + (size_t)px * 8) = h;
    return;
  }
  int e = (blockIdx.x - 2048) * 256 + threadIdx.x;  // 229376 total
  int j = e & 7, l = (e >> 3) & 63, f = e >> 9;
  int l15 = l & 15, q8 = (l >> 4) * 8;
  float v;
  if (f < 8)        { int mb = f >> 1, kb = f & 1;
                      v = Qp[(kb*32 + q8 + j) * 64 + mb*16 + l15]; }
  else if (f < 80)  { int g = f - 8, t = g >> 3, mb = (g >> 1) & 3, kb = g & 1;
                      v = Kp[(kb*32 + q8 + j) * 576 + t*64 + mb*16 + l15]; }
  else if (f < 152) { int g = f - 80, t = g >> 3, kb = (g >> 2) & 1, nb = g & 3;
                      v = Vp[(kb*32 + q8 + j) * 576 + t*64 + nb*16 + l15]; }
  else if (f < 160) { int g = f - 152, kb = g >> 2, nb = g & 3;
                      v = W1[(kb*32 + q8 + j) * 64 + nb*16 + l15]; }
  else if (f < 304) { int g = f - 160, t = g >> 4, kb = (g >> 3) & 1, nb = g & 7;
                      v = F2[(t*64 + kb*32 + q8 + j) * 128 + nb*16 + l15]; }
  else              { int g = f - 304, t = g >> 4, kb = (g >> 2) & 3, nb = g & 3;
                      v = F3[(t*128 + kb*32 + q8 + j) * 64 + nb*16 + l15]; }
  out[e] = (_Float16)v;
}

// ---------------- attention + ff1, barrier-free, L2-direct weights ---------
// 512 thr = 8 waves; block = 2 rows; wave = 32 px (m=2). LDS: wave-private
// ff1 transpose scratch (8 x 2304 halves) + den table (8 x 64 f32) = 38 KB.
__global__ __launch_bounds__(512, 4) void attn_ff1(
    const _Float16* __restrict__ xh, const _Float16* __restrict__ wf,
    const float* __restrict__ f1b, _Float16* __restrict__ t1g) {
  extern __shared__ _Float16 smem[];
  const int lane = threadIdx.x & 63, wid = threadIdx.x >> 6;
  const int l15 = lane & 15, q8 = (lane >> 4) * 8;
  const int row = blockIdx.x * 2 + (wid >> 2);
  const int rw = wid & 3;
  const int p0 = row * 128 + rw * 32;
  const int h = row & 127;
  const int w0 = rw * 32;
  const int oct0 = lane >> 4;               // x0 plane; x1 plane = oct0+4
  const _Float16* AK = wf + 4096;
  const _Float16* BV = wf + 40960;
  const _Float16* B1 = wf + 77824;
  _Float16* myt = smem + wid * 2304;                  // wave-private
  float* dent = (float*)(smem + 18432) + wid * 64;    // wave-private

  // own-x fragments + q^T tiles
  half8 ax0[2], ax1[2];
#pragma unroll
  for (int m = 0; m < 2; ++m) {
    const size_t px = (size_t)(p0 + m * 16 + l15);
    ax0[m] = ldfrag(xh + (size_t)oct0 * PLANE + px * 8);
    ax1[m] = ldfrag(xh + (size_t)(oct0 + 4) * PLANE + px * 8);
  }
  f32x4 qT[2][4];
#pragma unroll
  for (int cb = 0; cb < 4; ++cb) {
    half8 aq0 = ldfrag(wf + (cb * 2 + 0) * 512 + lane * 8);
    half8 aq1 = ldfrag(wf + (cb * 2 + 1) * 512 + lane * 8);
#pragma unroll
    for (int m = 0; m < 2; ++m) {
      f32x4 c = {};
      c = mfma16(aq0, ax0[m], c);
      c = mfma16(aq1, ax1[m], c);
      qT[m][cb] = c;
    }
  }

  auto load_tap = [&](int t, half8 (&x0)[2], half8 (&x1)[2]) {
    const int dh = t / 3 - 1, dw = t % 3 - 1;
    const bool rk = (unsigned)(h + dh) < 128u;
#pragma unroll
    for (int m = 0; m < 2; ++m) {
      const bool cv = rk && ((unsigned)(w0 + m * 16 + l15 + dw) < 128u);
      const size_t px = (size_t)(p0 + m * 16 + l15 + dh * 128 + dw);
      x0[m] = cv ? ldfrag(xh + (size_t)oct0 * PLANE + px * 8) : zfrag();
      x1[m] = cv ? ldfrag(xh + (size_t)(oct0 + 4) * PLANE + px * 8) : zfrag();
    }
  };

  float den0[2] = {0.f, 0.f}, den1[2] = {0.f, 0.f};
  // kf fragments from L2 (coalesced 1 KB reads), shared across both m
  auto score_tap = [&](int t, half8 (&x0)[2], half8 (&x1)[2],
                       float (&e0)[2], float (&e1)[2]) {
    const int dh = t / 3 - 1;
    const bool rowok = (unsigned)(h + dh) < 128u;
    half8 kf[8];
    if (rowok) {
#pragma unroll
      for (int f = 0; f < 8; ++f)
        kf[f] = ldfrag(AK + (size_t)(t * 8 + f) * 512 + lane * 8);
    }
#pragma unroll
    for (int m = 0; m < 2; ++m) {
      float pa = 0.f, pb = 0.f;
      if (rowok) {
#pragma unroll
        for (int cb = 0; cb < 4; ++cb) {
          f32x4 c = {};
          c = mfma16(kf[cb * 2 + 0], x0[m], c);
          c = mfma16(kf[cb * 2 + 1], x1[m], c);
          float d = qT[m][cb].x * c.x + qT[m][cb].y * c.y
                  + qT[m][cb].z * c.z + qT[m][cb].w * c.w;
          if (cb < 2) pa += d; else pb += d;
        }
        pa += __shfl_xor(pa, 16, 64); pa += __shfl_xor(pa, 32, 64);
        pb += __shfl_xor(pb, 16, 64); pb += __shfl_xor(pb, 32, 64);
      }
      e0[m] = __expf(pa * (1.f / 3.f));
      e1[m] = __expf(pb * (1.f / 3.f));
      den0[m] += e0[m]; den1[m] += e1[m];
    }
  };

  half8 sx0[2], sx1[2];
  load_tap(0, sx0, sx1);

  float e0c[2], e1c[2];
  score_tap(0, sx0, sx1, e0c, e1c);

  f32x4 at[2][4];
#pragma unroll
  for (int m = 0; m < 2; ++m)
#pragma unroll
    for (int nb = 0; nb < 4; ++nb) at[m][nb] = f32x4{};

#pragma unroll
  for (int t = 0; t < 9; ++t) {
    const bool rowok = (unsigned)(h + (t / 3 - 1)) < 128u;
    half8 nx0[2], nx1[2];
    if (t < 8) load_tap(t + 1, nx0, nx1);   // t+1 x-loads in flight
    if (rowok) {
      half8 vf[8];
#pragma unroll
      for (int f = 0; f < 8; ++f)
        vf[f] = ldfrag(BV + (size_t)(t * 8 + f) * 512 + lane * 8);
#pragma unroll
      for (int m = 0; m < 2; ++m) {
        _Float16 h0 = (_Float16)e0c[m], h1 = (_Float16)e1c[m];
        half8 b0 = {h0, h0, h0, h0, h0, h0, h0, h0};
        half8 b1 = {h1, h1, h1, h1, h1, h1, h1, h1};
        half8 s00 = sx0[m] * b0, s01 = sx1[m] * b0;
        half8 s10 = sx0[m] * b1, s11 = sx1[m] * b1;
#pragma unroll
        for (int nb = 0; nb < 2; ++nb) {
          at[m][nb]     = mfma16(s00, vf[0 * 4 + nb],     at[m][nb]);
          at[m][nb]     = mfma16(s01, vf[1 * 4 + nb],     at[m][nb]);
          at[m][nb + 2] = mfma16(s10, vf[0 * 4 + nb + 2], at[m][nb + 2]);
          at[m][nb + 2] = mfma16(s11, vf[1 * 4 + nb + 2], at[m][nb + 2]);
        }
      }
    }
    if (t < 8) {
      float e0n[2], e1n[2];
      score_tap(t + 1, nx0, nx1, e0n, e1n);
#pragma unroll
      for (int m = 0; m < 2; ++m) {
        sx0[m] = nx0[m]; sx1[m] = nx1[m];
        e0c[m] = e0n[m]; e1c[m] = e1n[m];
      }
    }
  }

  // per-pixel 1/den via wave-private LDS table (no barrier needed)
#pragma unroll
  for (int m = 0; m < 2; ++m) {
    dent[(m * 2 + 0) * 16 + l15] = den0[m];
    dent[(m * 2 + 1) * 16 + l15] = den1[m];
  }
  f32x4 iv[2][2];
#pragma unroll
  for (int m = 0; m < 2; ++m)
#pragma unroll
    for (int hd = 0; hd < 2; ++hd) {
      f32x4 dv = *(const f32x4*)(dent + (m * 2 + hd) * 16 + (lane >> 4) * 4);
      iv[m][hd] = f32x4{1.f / dv.x, 1.f / dv.y, 1.f / dv.z, 1.f / dv.w};
    }

  // ff1: normalize + wave-private transpose -> GEMM -> plane scatter
#pragma unroll
  for (int m = 0; m < 2; ++m)
#pragma unroll
    for (int nb = 0; nb < 4; ++nb) {
      const int hd = nb >> 1;
#pragma unroll
      for (int r = 0; r < 4; ++r)
        myt[m * 1152 + ((lane >> 4) * 4 + r) * 72 + nb * 16 + l15] =
            (_Float16)(at[m][nb][r] * iv[m][hd][r]);
    }
#pragma unroll
  for (int m = 0; m < 2; ++m) {
    half8 aa0 = ldfrag(myt + m * 1152 + l15 * 72 + q8);
    half8 aa1 = ldfrag(myt + m * 1152 + l15 * 72 + 32 + q8);
#pragma unroll
    for (int nb = 0; nb < 4; ++nb) {
      f32x4 c = {};
      c = mfma16(aa0, ldfrag(B1 + (0 * 4 + nb) * 512 + lane * 8), c);
      c = mfma16(aa1, ldfrag(B1 + (1 * 4 + nb) * 512 + lane * 8), c);
      float bv = f1b[nb * 16 + l15];
      const int ch = nb * 16 + l15;
      const size_t pbase = (size_t)(ch >> 3) * PLANE + (ch & 7);
#pragma unroll
      for (int r = 0; r < 4; ++r) {
        float v = fmaxf(c[r] + bv, 0.f);
        size_t px = (size_t)(p0 + m * 16 + (lane >> 4) * 4 + r);
        t1g[pbase + px * 8] = (_Float16)v;
      }
    }
  }
}

// ---------------- 3x3 conv, N-split, L2-direct weights, barrier-free -------
// Block = 2 rows x (COUT/2) channels; no LDS.
template <int KB, int NBL, int COUT>
__global__ __launch_bounds__(512, 4) void conv3x3(
    const _Float16* __restrict__ in, const _Float16* __restrict__ wfrag,
    const float* __restrict__ bias, void* __restrict__ outp, int out_fp32) {
  const int lane = threadIdx.x & 63, wid = threadIdx.x >> 6;
  const int l15 = lane & 15;
  const int nh = blockIdx.x & 1;
  const int pairIdx = blockIdx.x >> 1;
  const int row = pairIdx * 2 + (wid >> 2);
  const int rw = wid & 3;
  const int p0 = row * 128 + rw * 32;
  const int h = row & 127;
  const int w0 = rw * 32;
  const int NBF = COUT / 16;
  const int oct0 = lane >> 4;

  f32x4 acc[2][NBL];
#pragma unroll
  for (int m = 0; m < 2; ++m)
#pragma unroll
    for (int nb = 0; nb < NBL; ++nb) acc[m][nb] = f32x4{};

  half8 a[2][KB];
  {  // tap-0 prologue A-loads
    const bool rk = (unsigned)(h - 1) < 128u;
#pragma unroll
    for (int m = 0; m < 2; ++m) {
      const bool cv = rk && ((unsigned)(w0 + m * 16 + l15 - 1) < 128u);
      const size_t px = (size_t)(p0 + m * 16 + l15 - 129);
#pragma unroll
      for (int kb = 0; kb < KB; ++kb)
        a[m][kb] = cv ? ldfrag(in + (size_t)(kb * 4 + oct0) * PLANE + px * 8) : zfrag();
    }
  }

#pragma unroll
  for (int t = 0; t < 9; ++t) {
    const int dh = t / 3 - 1;
    const bool rowok = (unsigned)(h + dh) < 128u;
    half8 an[2][KB];
    if (t < 8) {                            // prefetch tap t+1 BEFORE compute
      const int dh2 = (t + 1) / 3 - 1, dw2 = (t + 1) % 3 - 1;
      const bool rk2 = (unsigned)(h + dh2) < 128u;
#pragma unroll
      for (int m = 0; m < 2; ++m) {
        const bool cv = rk2 && ((unsigned)(w0 + m * 16 + l15 + dw2) < 128u);
        const size_t px = (size_t)(p0 + m * 16 + l15 + dh2 * 128 + dw2);
#pragma unroll
        for (int kb = 0; kb < KB; ++kb)
          an[m][kb] = cv ? ldfrag(in + (size_t)(kb * 4 + oct0) * PLANE + px * 8) : zfrag();
      }
    }
    if (rowok) {
#pragma unroll
      for (int nb = 0; nb < NBL; ++nb) {
#pragma unroll
        for (int kb = 0; kb < KB; ++kb) {
          half8 b = ldfrag(wfrag + (size_t)((t * KB + kb) * NBF + nh * NBL + nb) * 512
                           + lane * 8);
          acc[0][nb] = mfma16(a[0][kb], b, acc[0][nb]);
          acc[1][nb] = mfma16(a[1][kb], b, acc[1][nb]);
        }
      }
    }
    if (t < 8) {
#pragma unroll
      for (int m = 0; m < 2; ++m)
#pragma unroll
        for (int kb = 0; kb < KB; ++kb) a[m][kb] = an[m][kb];
    }
  }

#pragma unroll
  for (int m = 0; m < 2; ++m)
#pragma unroll
    for (int nb = 0; nb < NBL; ++nb) {
      const int ch = nh * NBL * 16 + nb * 16 + l15;
      float bv = bias[ch];
#pragma unroll
      for (int r = 0; r < 4; ++r) {
        float v = fmaxf(acc[m][nb][r] + bv, 0.f);
        size_t px = (size_t)(p0 + m * 16 + (lane >> 4) * 4 + r);
        if (out_fp32) {
          ((float*)outp)[px * COUT + ch] = v;        // final: pixel-major fp32
        } else {
          ((_Float16*)outp)[(size_t)(ch >> 3) * PLANE + px * 8 + (ch & 7)] = (_Float16)v;
        }
      }
    }
}

extern "C" void kernel_launch(void* const* d_in, const int* in_sizes, int n_in,
                              void* d_out, int out_size, void* d_ws, size_t ws_size,
                              hipStream_t stream) {
  (void)in_sizes; (void)n_in; (void)out_size; (void)ws_size;
  const float* x   = (const float*)d_in[0];
  const float* Kp  = (const float*)d_in[1];
  const float* Vp  = (const float*)d_in[2];
  const float* Qp  = (const float*)d_in[3];
  const float* f1w = (const float*)d_in[4];
  const float* f1b = (const float*)d_in[5];
  const float* f2w = (const float*)d_in[6];
  const float* f2b = (const float*)d_in[7];
  const float* f3w = (const float*)d_in[8];
  const float* f3b = (const float*)d_in[9];

  // ws (halves): xh 8 planes [0,4194304) | wf [4194304,4423680)
  // | t1 8 planes [4423680,8617984) | t2 16 planes [8617984,17006592)  ~34 MB
  _Float16* xh  = (_Float16*)d_ws;
  _Float16* wf  = xh + 4194304;
  _Float16* t1g = wf + 229376;
  _Float16* t2g = t1g + 4194304;
  float* outp = (float*)d_out;

  prep<<<2944, 256, 0, stream>>>(x, Kp, Vp, Qp, f1w, f2w, f3w, xh, wf);
  attn_ff1<<<256, 512, 38912, stream>>>(xh, wf, f1b, t1g);
  conv3x3<2, 4, 128><<<512, 512, 0, stream>>>(t1g, wf + 81920, f2b, t2g, 0);
  conv3x3<4, 2, 64><<<512, 512, 0, stream>>>(t2g, wf + 155648, f3b, outp, 1);
}

// Round 11
// 142.056 us; speedup vs baseline: 1.2938x; 1.2938x over previous
//
#include <hip/hip_runtime.h>

// B=4, H=W=128, D=64, NH=2, hd=32, 9 taps. All inputs fp32; compute fp16 MFMA.
// R11 = R9 (best: LDS-staged weights, octet-plane activations, one-pass
// online-softmax attn, N-split convs) + CHUNKED EPILOGUES: ff1/conv2 outputs
// round-trip a wave-private LDS tile so every lane stores a full 16B half8
// into the octet planes (R10 counters showed 4.7x HBM write amplification
// from the old 2B-per-lane scatter: attn WRITE_SIZE 39.7MB for 8.4MB useful).

typedef _Float16 half8 __attribute__((ext_vector_type(8)));
typedef float f32x4 __attribute__((ext_vector_type(4)));

#define PLANE 524288  // 65536 pixels x 8 halves per plane

__device__ __forceinline__ f32x4 mfma16(half8 a, half8 b, f32x4 c) {
  return __builtin_amdgcn_mfma_f32_16x16x32_f16(a, b, c, 0, 0, 0);
}
__device__ __forceinline__ half8 ldfrag(const _Float16* p) { return *(const half8*)p; }
__device__ __forceinline__ half8 zfrag() { half8 z = {}; return z; }

__device__ __forceinline__ void gload_lds16(const _Float16* g, _Float16* l) {
  __builtin_amdgcn_global_load_lds(
      (const __attribute__((address_space(1))) void*)g,
      (__attribute__((address_space(3))) void*)l, 16, 0, 0);
}

// ---------------- prep: x -> fp16 octet planes + weight repack -------------
// blocks [0,2048): cvt, thread t -> px = b*32 + t/8, oct = t%8 (coalesced).
// blocks [2048,2944): weight repack into fragment layouts.
//   AQ  [mb4][kb2]      @ 0       AK  [t9][cb4][kb2]  @ 4096
//   BV  [t9][kb2][nb4]  @ 40960   B1  [kb2][nb4]      @ 77824
//   BF2 [t9][kb2][nb8]  @ 81920   BF3 [t9][kb4][nb4]  @ 155648  (229376 total)
__global__ __launch_bounds__(256) void prep(
    const float* __restrict__ x, const float* __restrict__ Kp,
    const float* __restrict__ Vp, const float* __restrict__ Qp,
    const float* __restrict__ W1, const float* __restrict__ F2,
    const float* __restrict__ F3, _Float16* __restrict__ xh,
    _Float16* __restrict__ out) {
  if (blockIdx.x < 2048) {
    const int t = threadIdx.x;
    const int px = blockIdx.x * 32 + (t >> 3);
    const int oct = t & 7;
    const float4* s = (const float4*)(x + (size_t)px * 64 + oct * 8);
    float4 a = s[0], b = s[1];
    half8 h = { (_Float16)a.x, (_Float16)a.y, (_Float16)a.z, (_Float16)a.w,
                (_Float16)b.x, (_Float16)b.y, (_Float16)b.z, (_Float16)b.w };
    *(half8*)(xh + (size_t)oct * PLANE + (size_t)px * 8) = h;
    return;
  }
  int e = (blockIdx.x - 2048) * 256 + threadIdx.x;  // 229376 total
  int j = e & 7, l = (e >> 3) & 63, f = e >> 9;
  int l15 = l & 15, q8 = (l >> 4) * 8;
  float v;
  if (f < 8)        { int mb = f >> 1, kb = f & 1;
                      v = Qp[(kb*32 + q8 + j) * 64 + mb*16 + l15]; }
  else if (f < 80)  { int g = f - 8, t = g >> 3, mb = (g >> 1) & 3, kb = g & 1;
                      v = Kp[(kb*32 + q8 + j) * 576 + t*64 + mb*16 + l15]; }
  else if (f < 152) { int g = f - 80, t = g >> 3, kb = (g >> 2) & 1, nb = g & 3;
                      v = Vp[(kb*32 + q8 + j) * 576 + t*64 + nb*16 + l15]; }
  else if (f < 160) { int g = f - 152, kb = g >> 2, nb = g & 3;
                      v = W1[(kb*32 + q8 + j) * 64 + nb*16 + l15]; }
  else if (f < 304) { int g = f - 160, t = g >> 4, kb = (g >> 3) & 1, nb = g & 7;
                      v = F2[(t*64 + kb*32 + q8 + j) * 128 + nb*16 + l15]; }
  else              { int g = f - 304, t = g >> 4, kb = (g >> 2) & 3, nb = g & 3;
                      v = F3[(t*128 + kb*32 + q8 + j) * 64 + nb*16 + l15]; }
  out[e] = (_Float16)v;
}

// ---------------- attention + ff1, one-pass online softmax -----------------
// 512 thr = 8 waves; block = 2 rows; wave = 32 px (m=2). LDS (halves):
// AK[0,36864) BV[36864,73728) B1[73728,77824) dentab(f32) @77824.
__global__ __launch_bounds__(512) void attn_ff1(
    const _Float16* __restrict__ xh, const _Float16* __restrict__ wf,
    const float* __restrict__ f1b, _Float16* __restrict__ t1g) {
  extern __shared__ _Float16 smem[];
  const int lane = threadIdx.x & 63, wid = threadIdx.x >> 6;
  const int l15 = lane & 15, q8 = (lane >> 4) * 8;
  const int row = blockIdx.x * 2 + (wid >> 2);
  const int rw = wid & 3;
  const int p0 = row * 128 + rw * 32;
  const int h = row & 127;
  const int w0 = rw * 32;
  const int oct0 = lane >> 4;               // x0 plane; x1 plane = oct0+4
  float* dent = (float*)(smem + 77824) + wid * 64;

  // stage AK+BV+B1 (152 frags, 19/wave); in flight during qT + prologue
  {
    const _Float16* gw = wf + 4096 + (size_t)(wid * 19) * 512;
    _Float16* lw = smem + wid * 19 * 512;
    for (int i = 0; i < 19; ++i)
      gload_lds16(gw + i * 512 + lane * 8, lw + i * 512);
  }

  // own-x fragments + q^T tiles
  half8 ax0[2], ax1[2];
#pragma unroll
  for (int m = 0; m < 2; ++m) {
    const size_t px = (size_t)(p0 + m * 16 + l15);
    ax0[m] = ldfrag(xh + (size_t)oct0 * PLANE + px * 8);
    ax1[m] = ldfrag(xh + (size_t)(oct0 + 4) * PLANE + px * 8);
  }
  f32x4 qT[2][4];
#pragma unroll
  for (int cb = 0; cb < 4; ++cb) {
    half8 aq0 = ldfrag(wf + (cb * 2 + 0) * 512 + lane * 8);
    half8 aq1 = ldfrag(wf + (cb * 2 + 1) * 512 + lane * 8);
#pragma unroll
    for (int m = 0; m < 2; ++m) {
      f32x4 c = {};
      c = mfma16(aq0, ax0[m], c);
      c = mfma16(aq1, ax1[m], c);
      qT[m][cb] = c;
    }
  }

  auto load_tap = [&](int t, half8 (&x0)[2], half8 (&x1)[2]) {
    const int dh = t / 3 - 1, dw = t % 3 - 1;
    const bool rk = (unsigned)(h + dh) < 128u;
#pragma unroll
    for (int m = 0; m < 2; ++m) {
      const bool cv = rk && ((unsigned)(w0 + m * 16 + l15 + dw) < 128u);
      const size_t px = (size_t)(p0 + m * 16 + l15 + dh * 128 + dw);
      x0[m] = cv ? ldfrag(xh + (size_t)oct0 * PLANE + px * 8) : zfrag();
      x1[m] = cv ? ldfrag(xh + (size_t)(oct0 + 4) * PLANE + px * 8) : zfrag();
    }
  };

  float den0[2] = {0.f, 0.f}, den1[2] = {0.f, 0.f};
  auto score_tap = [&](int t, half8 (&x0)[2], half8 (&x1)[2],
                       float (&e0)[2], float (&e1)[2]) {
    const int dh = t / 3 - 1;
    const bool rowok = (unsigned)(h + dh) < 128u;
    half8 kf[8];
    if (rowok) {
#pragma unroll
      for (int f = 0; f < 8; ++f)
        kf[f] = ldfrag(smem + (t * 8 + f) * 512 + lane * 8);
    }
#pragma unroll
    for (int m = 0; m < 2; ++m) {
      float pa = 0.f, pb = 0.f;
      if (rowok) {
#pragma unroll
        for (int cb = 0; cb < 4; ++cb) {
          f32x4 c = {};
          c = mfma16(kf[cb * 2 + 0], x0[m], c);
          c = mfma16(kf[cb * 2 + 1], x1[m], c);
          float d = qT[m][cb].x * c.x + qT[m][cb].y * c.y
                  + qT[m][cb].z * c.z + qT[m][cb].w * c.w;
          if (cb < 2) pa += d; else pb += d;
        }
        pa += __shfl_xor(pa, 16, 64); pa += __shfl_xor(pa, 32, 64);
        pb += __shfl_xor(pb, 16, 64); pb += __shfl_xor(pb, 32, 64);
      }
      e0[m] = __expf(pa * (1.f / 3.f));
      e1[m] = __expf(pb * (1.f / 3.f));
      den0[m] += e0[m]; den1[m] += e1[m];
    }
  };

  half8 sx0[2], sx1[2];
  load_tap(0, sx0, sx1);                    // tap-0 loads overlap staging drain

  __syncthreads();                          // staging complete

  float e0c[2], e1c[2];
  score_tap(0, sx0, sx1, e0c, e1c);

  const _Float16* BVl = smem + 36864;
  f32x4 at[2][4];
#pragma unroll
  for (int m = 0; m < 2; ++m)
#pragma unroll
    for (int nb = 0; nb < 4; ++nb) at[m][nb] = f32x4{};

#pragma unroll
  for (int t = 0; t < 9; ++t) {
    const bool rowok = (unsigned)(h + (t / 3 - 1)) < 128u;
    half8 nx0[2], nx1[2];
    if (t < 8) load_tap(t + 1, nx0, nx1);   // t+1 loads in flight
    if (rowok) {
      half8 vf[8];
#pragma unroll
      for (int f = 0; f < 8; ++f) vf[f] = ldfrag(BVl + (t * 8 + f) * 512 + lane * 8);
#pragma unroll
      for (int m = 0; m < 2; ++m) {
        _Float16 h0 = (_Float16)e0c[m], h1 = (_Float16)e1c[m];
        half8 b0 = {h0, h0, h0, h0, h0, h0, h0, h0};
        half8 b1 = {h1, h1, h1, h1, h1, h1, h1, h1};
        half8 s00 = sx0[m] * b0, s01 = sx1[m] * b0;
        half8 s10 = sx0[m] * b1, s11 = sx1[m] * b1;
#pragma unroll
        for (int nb = 0; nb < 2; ++nb) {
          at[m][nb]     = mfma16(s00, vf[0 * 4 + nb],     at[m][nb]);
          at[m][nb]     = mfma16(s01, vf[1 * 4 + nb],     at[m][nb]);
          at[m][nb + 2] = mfma16(s10, vf[0 * 4 + nb + 2], at[m][nb + 2]);
          at[m][nb + 2] = mfma16(s11, vf[1 * 4 + nb + 2], at[m][nb + 2]);
        }
      }
    }
    if (t < 8) {
      float e0n[2], e1n[2];
      score_tap(t + 1, nx0, nx1, e0n, e1n);
#pragma unroll
      for (int m = 0; m < 2; ++m) {
        sx0[m] = nx0[m]; sx1[m] = nx1[m];
        e0c[m] = e0n[m]; e1c[m] = e1n[m];
      }
    }
  }

  // per-pixel 1/den via per-wave LDS table
#pragma unroll
  for (int m = 0; m < 2; ++m) {
    dent[(m * 2 + 0) * 16 + l15] = den0[m];
    dent[(m * 2 + 1) * 16 + l15] = den1[m];
  }
  f32x4 iv[2][2];
#pragma unroll
  for (int m = 0; m < 2; ++m)
#pragma unroll
    for (int hd = 0; hd < 2; ++hd) {
      f32x4 dv = *(const f32x4*)(dent + (m * 2 + hd) * 16 + (lane >> 4) * 4);
      iv[m][hd] = f32x4{1.f / dv.x, 1.f / dv.y, 1.f / dv.z, 1.f / dv.w};
    }

  // -------- ff1: normalize + transpose -> GEMM -> CHUNKED plane store ------
  __syncthreads();                          // done reading AK/BV
  _Float16* myt = smem + wid * 2304;        // wave-private 2x1152
#pragma unroll
  for (int m = 0; m < 2; ++m)
#pragma unroll
    for (int nb = 0; nb < 4; ++nb) {
      const int hd = nb >> 1;
#pragma unroll
      for (int r = 0; r < 4; ++r)
        myt[m * 1152 + ((lane >> 4) * 4 + r) * 72 + nb * 16 + l15] =
            (_Float16)(at[m][nb][r] * iv[m][hd][r]);
    }
  const _Float16* B1l = smem + 73728;
  const int pxl = lane >> 2;                // chunk readback: pixel 0..15
  const int co0 = lane & 3;                 // octs co0 and co0+4
#pragma unroll
  for (int m = 0; m < 2; ++m) {
    _Float16* T = myt + m * 1152;           // input tile; reused as output tile
    half8 aa0 = ldfrag(T + l15 * 72 + q8);
    half8 aa1 = ldfrag(T + l15 * 72 + 32 + q8);
#pragma unroll
    for (int nb = 0; nb < 4; ++nb) {
      f32x4 c = {};
      c = mfma16(aa0, ldfrag(B1l + (0 * 4 + nb) * 512 + lane * 8), c);
      c = mfma16(aa1, ldfrag(B1l + (1 * 4 + nb) * 512 + lane * 8), c);
      float bv = f1b[nb * 16 + l15];
#pragma unroll
      for (int r = 0; r < 4; ++r)           // overwrite tile slot m (input dead)
        T[((lane >> 4) * 4 + r) * 72 + nb * 16 + l15] =
            (_Float16)fmaxf(c[r] + bv, 0.f);
    }
    // readback 16B chunks, contiguous 16B stores (16 lanes/oct -> 256B runs)
    const size_t pxg = (size_t)(p0 + m * 16 + pxl);
    half8 h0 = ldfrag(T + pxl * 72 + co0 * 8);
    half8 h1 = ldfrag(T + pxl * 72 + (co0 + 4) * 8);
    *(half8*)(t1g + (size_t)co0 * PLANE + pxg * 8) = h0;
    *(half8*)(t1g + (size_t)(co0 + 4) * PLANE + pxg * 8) = h1;
  }
}

// ---------------- 3x3 conv, N-split, octet-plane I/O -----------------------
// Block = 2 rows x (COUT/2) channels; LDS 72 KB weights -> 2 blocks/CU.
// fp16 output via chunked epilogue (weight LDS reused as scratch after
// end-of-taps barrier); fp32 final output pixel-major (already contiguous).
template <int KB, int NBL, int COUT>
__global__ __launch_bounds__(512, 2) void conv3x3(
    const _Float16* __restrict__ in, const _Float16* __restrict__ wfrag,
    const float* __restrict__ bias, void* __restrict__ outp, int out_fp32) {
  extern __shared__ _Float16 smem[];
  const int lane = threadIdx.x & 63, wid = threadIdx.x >> 6;
  const int l15 = lane & 15;
  const int nh = blockIdx.x & 1;
  const int pairIdx = blockIdx.x >> 1;
  const int row = pairIdx * 2 + (wid >> 2);
  const int rw = wid & 3;
  const int p0 = row * 128 + rw * 32;
  const int h = row & 127;
  const int w0 = rw * 32;
  const int NBF = COUT / 16;
  const int oct0 = lane >> 4;

  {
    for (int s = 0; s < 9; ++s) {
      int f = wid * 9 + s;
      int t = f >> 3, r = f & 7, kb = r / NBL, i = r % NBL;
      const _Float16* g = wfrag + (size_t)((t * KB + kb) * NBF + nh * NBL + i) * 512;
      gload_lds16(g + lane * 8, smem + f * 512);
    }
  }

  f32x4 acc[2][NBL];
#pragma unroll
  for (int m = 0; m < 2; ++m)
#pragma unroll
    for (int nb = 0; nb < NBL; ++nb) acc[m][nb] = f32x4{};

  half8 a[2][KB];
  {  // tap-0 prologue A-loads before the barrier
    const bool rk = (unsigned)(h - 1) < 128u;
#pragma unroll
    for (int m = 0; m < 2; ++m) {
      const bool cv = rk && ((unsigned)(w0 + m * 16 + l15 - 1) < 128u);
      const size_t px = (size_t)(p0 + m * 16 + l15 - 129);
#pragma unroll
      for (int kb = 0; kb < KB; ++kb)
        a[m][kb] = cv ? ldfrag(in + (size_t)(kb * 4 + oct0) * PLANE + px * 8) : zfrag();
    }
  }

  __syncthreads();

#pragma unroll
  for (int t = 0; t < 9; ++t) {
    const int dh = t / 3 - 1;
    const bool rowok = (unsigned)(h + dh) < 128u;
    half8 an[2][KB];
    if (t < 8) {                            // prefetch tap t+1 BEFORE compute
      const int dh2 = (t + 1) / 3 - 1, dw2 = (t + 1) % 3 - 1;
      const bool rk2 = (unsigned)(h + dh2) < 128u;
#pragma unroll
      for (int m = 0; m < 2; ++m) {
        const bool cv = rk2 && ((unsigned)(w0 + m * 16 + l15 + dw2) < 128u);
        const size_t px = (size_t)(p0 + m * 16 + l15 + dh2 * 128 + dw2);
#pragma unroll
        for (int kb = 0; kb < KB; ++kb)
          an[m][kb] = cv ? ldfrag(in + (size_t)(kb * 4 + oct0) * PLANE + px * 8) : zfrag();
      }
    }
    if (rowok) {
#pragma unroll
      for (int nb = 0; nb < NBL; ++nb) {
#pragma unroll
        for (int kb = 0; kb < KB; ++kb) {
          half8 b = ldfrag(smem + (size_t)((t * KB + kb) * NBL + nb) * 512 + lane * 8);
          acc[0][nb] = mfma16(a[0][kb], b, acc[0][nb]);
          acc[1][nb] = mfma16(a[1][kb], b, acc[1][nb]);
        }
      }
    }
    if (t < 8) {
#pragma unroll
      for (int m = 0; m < 2; ++m)
#pragma unroll
        for (int kb = 0; kb < KB; ++kb) a[m][kb] = an[m][kb];
    }
  }

  if (out_fp32) {
    // final output: pixel-major fp32, quad-contiguous 64B runs — direct store
#pragma unroll
    for (int m = 0; m < 2; ++m)
#pragma unroll
      for (int nb = 0; nb < NBL; ++nb) {
        const int ch = nh * NBL * 16 + nb * 16 + l15;
        float bv = bias[ch];
#pragma unroll
        for (int r = 0; r < 4; ++r) {
          float v = fmaxf(acc[m][nb][r] + bv, 0.f);
          size_t px = (size_t)(p0 + m * 16 + (lane >> 4) * 4 + r);
          ((float*)outp)[px * COUT + ch] = v;
        }
      }
  } else {
    // fp16 plane output: chunked epilogue through wave-private LDS scratch
    __syncthreads();                        // weights dead for ALL waves now
    _Float16* T = smem + wid * 1152;        // wave-private 16x72 tile
    const int pxl = lane >> 2, co0 = lane & 3;
#pragma unroll
    for (int m = 0; m < 2; ++m) {
#pragma unroll
      for (int nb = 0; nb < NBL; ++nb) {
        const int chl = nb * 16 + l15;      // local ch within N-half (0..63)
        float bv = bias[nh * NBL * 16 + chl];
#pragma unroll
        for (int r = 0; r < 4; ++r)
          T[((lane >> 4) * 4 + r) * 72 + chl] =
              (_Float16)fmaxf(acc[m][nb][r] + bv, 0.f);
      }
      const size_t pxg = (size_t)(p0 + m * 16 + pxl);
      half8 h0 = ldfrag(T + pxl * 72 + co0 * 8);
      half8 h1 = ldfrag(T + pxl * 72 + (co0 + 4) * 8);
      *(half8*)((_Float16*)outp + (size_t)(nh * 8 + co0) * PLANE + pxg * 8) = h0;
      *(half8*)((_Float16*)outp + (size_t)(nh * 8 + co0 + 4) * PLANE + pxg * 8) = h1;
    }
  }
}

extern "C" void kernel_launch(void* const* d_in, const int* in_sizes, int n_in,
                              void* d_out, int out_size, void* d_ws, size_t ws_size,
                              hipStream_t stream) {
  (void)in_sizes; (void)n_in; (void)out_size; (void)ws_size;
  const float* x   = (const float*)d_in[0];
  const float* Kp  = (const float*)d_in[1];
  const float* Vp  = (const float*)d_in[2];
  const float* Qp  = (const float*)d_in[3];
  const float* f1w = (const float*)d_in[4];
  const float* f1b = (const float*)d_in[5];
  const float* f2w = (const float*)d_in[6];
  const float* f2b = (const float*)d_in[7];
  const float* f3w = (const float*)d_in[8];
  const float* f3b = (const float*)d_in[9];

  // ws (halves): xh 8 planes [0,4194304) | wf [4194304,4423680)
  // | t1 8 planes [4423680,8617984) | t2 16 planes [8617984,17006592)  ~34 MB
  _Float16* xh  = (_Float16*)d_ws;
  _Float16* wf  = xh + 4194304;
  _Float16* t1g = wf + 229376;
  _Float16* t2g = t1g + 4194304;
  float* outp = (float*)d_out;

  (void)hipFuncSetAttribute((const void*)attn_ff1,
      hipFuncAttributeMaxDynamicSharedMemorySize, 157696);
  (void)hipFuncSetAttribute((const void*)conv3x3<2, 4, 128>,
      hipFuncAttributeMaxDynamicSharedMemorySize, 73728);
  (void)hipFuncSetAttribute((const void*)conv3x3<4, 2, 64>,
      hipFuncAttributeMaxDynamicSharedMemorySize, 73728);

  prep<<<2944, 256, 0, stream>>>(x, Kp, Vp, Qp, f1w, f2w, f3w, xh, wf);
  attn_ff1<<<256, 512, 157696, stream>>>(xh, wf, f1b, t1g);
  conv3x3<2, 4, 128><<<512, 512, 73728, stream>>>(t1g, wf + 81920, f2b, t2g, 0);
  conv3x3<4, 2, 64><<<512, 512, 73728, stream>>>(t2g, wf + 155648, f3b, outp, 1);
}

// Round 12
// 137.726 us; speedup vs baseline: 1.3345x; 1.0314x over previous
//
#include <hip/hip_runtime.h>

// B=4, H=W=128, D=64, NH=2, hd=32, 9 taps. All inputs fp32; compute fp16 MFMA.
// R12 = R11 (LDS-staged weights, octet-plane activations, one-pass online
// softmax, chunked epilogues) + DEEP A-LOAD PIPELINE: tap x-loads prefetched
// 3 taps ahead through a 4-slot register queue (attn + conv2; conv3 stays
// depth-1 for VGPR budget). Theory: un-hidden L2 latency on tap loads is the
// ~3x gap between pipe-busy arithmetic (~7us) and measured (~33us) in attn.

typedef _Float16 half8 __attribute__((ext_vector_type(8)));
typedef float f32x4 __attribute__((ext_vector_type(4)));

#define PLANE 524288  // 65536 pixels x 8 halves per plane

__device__ __forceinline__ f32x4 mfma16(half8 a, half8 b, f32x4 c) {
  return __builtin_amdgcn_mfma_f32_16x16x32_f16(a, b, c, 0, 0, 0);
}
__device__ __forceinline__ half8 ldfrag(const _Float16* p) { return *(const half8*)p; }
__device__ __forceinline__ half8 zfrag() { half8 z = {}; return z; }

__device__ __forceinline__ void gload_lds16(const _Float16* g, _Float16* l) {
  __builtin_amdgcn_global_load_lds(
      (const __attribute__((address_space(1))) void*)g,
      (__attribute__((address_space(3))) void*)l, 16, 0, 0);
}

// ---------------- prep: x -> fp16 octet planes + weight repack -------------
//   AQ  [mb4][kb2]      @ 0       AK  [t9][cb4][kb2]  @ 4096
//   BV  [t9][kb2][nb4]  @ 40960   B1  [kb2][nb4]      @ 77824
//   BF2 [t9][kb2][nb8]  @ 81920   BF3 [t9][kb4][nb4]  @ 155648  (229376 total)
__global__ __launch_bounds__(256) void prep(
    const float* __restrict__ x, const float* __restrict__ Kp,
    const float* __restrict__ Vp, const float* __restrict__ Qp,
    const float* __restrict__ W1, const float* __restrict__ F2,
    const float* __restrict__ F3, _Float16* __restrict__ xh,
    _Float16* __restrict__ out) {
  if (blockIdx.x < 2048) {
    const int t = threadIdx.x;
    const int px = blockIdx.x * 32 + (t >> 3);
    const int oct = t & 7;
    const float4* s = (const float4*)(x + (size_t)px * 64 + oct * 8);
    float4 a = s[0], b = s[1];
    half8 h = { (_Float16)a.x, (_Float16)a.y, (_Float16)a.z, (_Float16)a.w,
                (_Float16)b.x, (_Float16)b.y, (_Float16)b.z, (_Float16)b.w };
    *(half8*)(xh + (size_t)oct * PLANE + (size_t)px * 8) = h;
    return;
  }
  int e = (blockIdx.x - 2048) * 256 + threadIdx.x;  // 229376 total
  int j = e & 7, l = (e >> 3) & 63, f = e >> 9;
  int l15 = l & 15, q8 = (l >> 4) * 8;
  float v;
  if (f < 8)        { int mb = f >> 1, kb = f & 1;
                      v = Qp[(kb*32 + q8 + j) * 64 + mb*16 + l15]; }
  else if (f < 80)  { int g = f - 8, t = g >> 3, mb = (g >> 1) & 3, kb = g & 1;
                      v = Kp[(kb*32 + q8 + j) * 576 + t*64 + mb*16 + l15]; }
  else if (f < 152) { int g = f - 80, t = g >> 3, kb = (g >> 2) & 1, nb = g & 3;
                      v = Vp[(kb*32 + q8 + j) * 576 + t*64 + nb*16 + l15]; }
  else if (f < 160) { int g = f - 152, kb = g >> 2, nb = g & 3;
                      v = W1[(kb*32 + q8 + j) * 64 + nb*16 + l15]; }
  else if (f < 304) { int g = f - 160, t = g >> 4, kb = (g >> 3) & 1, nb = g & 7;
                      v = F2[(t*64 + kb*32 + q8 + j) * 128 + nb*16 + l15]; }
  else              { int g = f - 304, t = g >> 4, kb = (g >> 2) & 3, nb = g & 3;
                      v = F3[(t*128 + kb*32 + q8 + j) * 64 + nb*16 + l15]; }
  out[e] = (_Float16)v;
}

// ---------------- attention + ff1, one-pass online softmax -----------------
// 512 thr = 8 waves; block = 2 rows; wave = 32 px (m=2). LDS (halves):
// AK[0,36864) BV[36864,73728) B1[73728,77824) dentab(f32) @77824.
// x-tap loads flow through a 4-slot register queue, 3 taps ahead.
__global__ __launch_bounds__(512) void attn_ff1(
    const _Float16* __restrict__ xh, const _Float16* __restrict__ wf,
    const float* __restrict__ f1b, _Float16* __restrict__ t1g) {
  extern __shared__ _Float16 smem[];
  const int lane = threadIdx.x & 63, wid = threadIdx.x >> 6;
  const int l15 = lane & 15, q8 = (lane >> 4) * 8;
  const int row = blockIdx.x * 2 + (wid >> 2);
  const int rw = wid & 3;
  const int p0 = row * 128 + rw * 32;
  const int h = row & 127;
  const int w0 = rw * 32;
  const int oct0 = lane >> 4;               // x0 plane; x1 plane = oct0+4
  float* dent = (float*)(smem + 77824) + wid * 64;

  // stage AK+BV+B1 (152 frags, 19/wave); in flight during qT + prologue
  {
    const _Float16* gw = wf + 4096 + (size_t)(wid * 19) * 512;
    _Float16* lw = smem + wid * 19 * 512;
    for (int i = 0; i < 19; ++i)
      gload_lds16(gw + i * 512 + lane * 8, lw + i * 512);
  }

  // own-x fragments + q^T tiles
  half8 ax0[2], ax1[2];
#pragma unroll
  for (int m = 0; m < 2; ++m) {
    const size_t px = (size_t)(p0 + m * 16 + l15);
    ax0[m] = ldfrag(xh + (size_t)oct0 * PLANE + px * 8);
    ax1[m] = ldfrag(xh + (size_t)(oct0 + 4) * PLANE + px * 8);
  }
  f32x4 qT[2][4];
#pragma unroll
  for (int cb = 0; cb < 4; ++cb) {
    half8 aq0 = ldfrag(wf + (cb * 2 + 0) * 512 + lane * 8);
    half8 aq1 = ldfrag(wf + (cb * 2 + 1) * 512 + lane * 8);
#pragma unroll
    for (int m = 0; m < 2; ++m) {
      f32x4 c = {};
      c = mfma16(aq0, ax0[m], c);
      c = mfma16(aq1, ax1[m], c);
      qT[m][cb] = c;
    }
  }

  auto load_tap = [&](int t, half8 (&x0)[2], half8 (&x1)[2]) {
    const int dh = t / 3 - 1, dw = t % 3 - 1;
    const bool rk = (unsigned)(h + dh) < 128u;
#pragma unroll
    for (int m = 0; m < 2; ++m) {
      const bool cv = rk && ((unsigned)(w0 + m * 16 + l15 + dw) < 128u);
      const size_t px = (size_t)(p0 + m * 16 + l15 + dh * 128 + dw);
      x0[m] = cv ? ldfrag(xh + (size_t)oct0 * PLANE + px * 8) : zfrag();
      x1[m] = cv ? ldfrag(xh + (size_t)(oct0 + 4) * PLANE + px * 8) : zfrag();
    }
  };

  float den0[2] = {0.f, 0.f}, den1[2] = {0.f, 0.f};
  auto score_tap = [&](int t, half8 (&x0)[2], half8 (&x1)[2],
                       float (&e0)[2], float (&e1)[2]) {
    const int dh = t / 3 - 1;
    const bool rowok = (unsigned)(h + dh) < 128u;
    half8 kf[8];
    if (rowok) {
#pragma unroll
      for (int f = 0; f < 8; ++f)
        kf[f] = ldfrag(smem + (t * 8 + f) * 512 + lane * 8);
    }
#pragma unroll
    for (int m = 0; m < 2; ++m) {
      float pa = 0.f, pb = 0.f;
      if (rowok) {
#pragma unroll
        for (int cb = 0; cb < 4; ++cb) {
          f32x4 c = {};
          c = mfma16(kf[cb * 2 + 0], x0[m], c);
          c = mfma16(kf[cb * 2 + 1], x1[m], c);
          float d = qT[m][cb].x * c.x + qT[m][cb].y * c.y
                  + qT[m][cb].z * c.z + qT[m][cb].w * c.w;
          if (cb < 2) pa += d; else pb += d;
        }
        pa += __shfl_xor(pa, 16, 64); pa += __shfl_xor(pa, 32, 64);
        pb += __shfl_xor(pb, 16, 64); pb += __shfl_xor(pb, 32, 64);
      }
      e0[m] = __expf(pa * (1.f / 3.f));
      e1[m] = __expf(pb * (1.f / 3.f));
      den0[m] += e0[m]; den1[m] += e1[m];
    }
  };

  // 4-slot register queue, 3 taps in flight; prologue overlaps staging drain
  half8 q0[4][2], q1[4][2];
  load_tap(0, q0[0], q1[0]);
  load_tap(1, q0[1], q1[1]);
  load_tap(2, q0[2], q1[2]);

  __syncthreads();                          // staging complete

  float e0c[2], e1c[2];
  score_tap(0, q0[0], q1[0], e0c, e1c);

  const _Float16* BVl = smem + 36864;
  f32x4 at[2][4];
#pragma unroll
  for (int m = 0; m < 2; ++m)
#pragma unroll
    for (int nb = 0; nb < 4; ++nb) at[m][nb] = f32x4{};

#pragma unroll
  for (int t = 0; t < 9; ++t) {
    if (t + 3 < 9) load_tap(t + 3, q0[(t + 3) & 3], q1[(t + 3) & 3]);
    const bool rowok = (unsigned)(h + (t / 3 - 1)) < 128u;
    if (rowok) {
      half8 vf[8];
#pragma unroll
      for (int f = 0; f < 8; ++f) vf[f] = ldfrag(BVl + (t * 8 + f) * 512 + lane * 8);
#pragma unroll
      for (int m = 0; m < 2; ++m) {
        _Float16 h0 = (_Float16)e0c[m], h1 = (_Float16)e1c[m];
        half8 b0 = {h0, h0, h0, h0, h0, h0, h0, h0};
        half8 b1 = {h1, h1, h1, h1, h1, h1, h1, h1};
        half8 s00 = q0[t & 3][m] * b0, s01 = q1[t & 3][m] * b0;
        half8 s10 = q0[t & 3][m] * b1, s11 = q1[t & 3][m] * b1;
#pragma unroll
        for (int nb = 0; nb < 2; ++nb) {
          at[m][nb]     = mfma16(s00, vf[0 * 4 + nb],     at[m][nb]);
          at[m][nb]     = mfma16(s01, vf[1 * 4 + nb],     at[m][nb]);
          at[m][nb + 2] = mfma16(s10, vf[0 * 4 + nb + 2], at[m][nb + 2]);
          at[m][nb + 2] = mfma16(s11, vf[1 * 4 + nb + 2], at[m][nb + 2]);
        }
      }
    }
    if (t < 8) {
      float e0n[2], e1n[2];
      score_tap(t + 1, q0[(t + 1) & 3], q1[(t + 1) & 3], e0n, e1n);
#pragma unroll
      for (int m = 0; m < 2; ++m) { e0c[m] = e0n[m]; e1c[m] = e1n[m]; }
    }
  }

  // per-pixel 1/den via per-wave LDS table
#pragma unroll
  for (int m = 0; m < 2; ++m) {
    dent[(m * 2 + 0) * 16 + l15] = den0[m];
    dent[(m * 2 + 1) * 16 + l15] = den1[m];
  }
  f32x4 iv[2][2];
#pragma unroll
  for (int m = 0; m < 2; ++m)
#pragma unroll
    for (int hd = 0; hd < 2; ++hd) {
      f32x4 dv = *(const f32x4*)(dent + (m * 2 + hd) * 16 + (lane >> 4) * 4);
      iv[m][hd] = f32x4{1.f / dv.x, 1.f / dv.y, 1.f / dv.z, 1.f / dv.w};
    }

  // -------- ff1: normalize + transpose -> GEMM -> CHUNKED plane store ------
  __syncthreads();                          // done reading AK/BV
  _Float16* myt = smem + wid * 2304;        // wave-private 2x1152
#pragma unroll
  for (int m = 0; m < 2; ++m)
#pragma unroll
    for (int nb = 0; nb < 4; ++nb) {
      const int hd = nb >> 1;
#pragma unroll
      for (int r = 0; r < 4; ++r)
        myt[m * 1152 + ((lane >> 4) * 4 + r) * 72 + nb * 16 + l15] =
            (_Float16)(at[m][nb][r] * iv[m][hd][r]);
    }
  const _Float16* B1l = smem + 73728;
  const int pxl = lane >> 2;                // chunk readback: pixel 0..15
  const int co0 = lane & 3;                 // octs co0 and co0+4
#pragma unroll
  for (int m = 0; m < 2; ++m) {
    _Float16* T = myt + m * 1152;           // input tile; reused as output tile
    half8 aa0 = ldfrag(T + l15 * 72 + q8);
    half8 aa1 = ldfrag(T + l15 * 72 + 32 + q8);
#pragma unroll
    for (int nb = 0; nb < 4; ++nb) {
      f32x4 c = {};
      c = mfma16(aa0, ldfrag(B1l + (0 * 4 + nb) * 512 + lane * 8), c);
      c = mfma16(aa1, ldfrag(B1l + (1 * 4 + nb) * 512 + lane * 8), c);
      float bv = f1b[nb * 16 + l15];
#pragma unroll
      for (int r = 0; r < 4; ++r)           // overwrite tile slot m (input dead)
        T[((lane >> 4) * 4 + r) * 72 + nb * 16 + l15] =
            (_Float16)fmaxf(c[r] + bv, 0.f);
    }
    // readback 16B chunks, contiguous 16B stores (16 lanes/oct -> 256B runs)
    const size_t pxg = (size_t)(p0 + m * 16 + pxl);
    half8 h0 = ldfrag(T + pxl * 72 + co0 * 8);
    half8 h1 = ldfrag(T + pxl * 72 + (co0 + 4) * 8);
    *(half8*)(t1g + (size_t)co0 * PLANE + pxg * 8) = h0;
    *(half8*)(t1g + (size_t)(co0 + 4) * PLANE + pxg * 8) = h1;
  }
}

// ---------------- 3x3 conv, N-split, octet-plane I/O -----------------------
// Block = 2 rows x (COUT/2) channels; LDS 72 KB weights -> 2 blocks/CU.
// DEPTH-deep A-load register queue (DEPTH+1 slots). lb(512,4) caps VGPR at
// 128 so 2 blocks/CU (4 waves/SIMD) holds.
template <int KB, int NBL, int COUT, int DEPTH>
__global__ __launch_bounds__(512, 4) void conv3x3(
    const _Float16* __restrict__ in, const _Float16* __restrict__ wfrag,
    const float* __restrict__ bias, void* __restrict__ outp, int out_fp32) {
  extern __shared__ _Float16 smem[];
  constexpr int NS = DEPTH + 1;
  const int lane = threadIdx.x & 63, wid = threadIdx.x >> 6;
  const int l15 = lane & 15;
  const int nh = blockIdx.x & 1;
  const int pairIdx = blockIdx.x >> 1;
  const int row = pairIdx * 2 + (wid >> 2);
  const int rw = wid & 3;
  const int p0 = row * 128 + rw * 32;
  const int h = row & 127;
  const int w0 = rw * 32;
  const int NBF = COUT / 16;
  const int oct0 = lane >> 4;

  {
    for (int s = 0; s < 9; ++s) {
      int f = wid * 9 + s;
      int t = f >> 3, r = f & 7, kb = r / NBL, i = r % NBL;
      const _Float16* g = wfrag + (size_t)((t * KB + kb) * NBF + nh * NBL + i) * 512;
      gload_lds16(g + lane * 8, smem + f * 512);
    }
  }

  f32x4 acc[2][NBL];
#pragma unroll
  for (int m = 0; m < 2; ++m)
#pragma unroll
    for (int nb = 0; nb < NBL; ++nb) acc[m][nb] = f32x4{};

  auto load_conv = [&](int t, half8 (&dst)[2][KB]) {
    const int dh = t / 3 - 1, dw = t % 3 - 1;
    const bool rk = (unsigned)(h + dh) < 128u;
#pragma unroll
    for (int m = 0; m < 2; ++m) {
      const bool cv = rk && ((unsigned)(w0 + m * 16 + l15 + dw) < 128u);
      const size_t px = (size_t)(p0 + m * 16 + l15 + dh * 128 + dw);
#pragma unroll
      for (int kb = 0; kb < KB; ++kb)
        dst[m][kb] = cv ? ldfrag(in + (size_t)(kb * 4 + oct0) * PLANE + px * 8) : zfrag();
    }
  };

  half8 aq[NS][2][KB];
#pragma unroll
  for (int d = 0; d < DEPTH; ++d) load_conv(d, aq[d]);  // overlap staging

  __syncthreads();

#pragma unroll
  for (int t = 0; t < 9; ++t) {
    if (t + DEPTH < 9) load_conv(t + DEPTH, aq[(t + DEPTH) % NS]);
    const bool rowok = (unsigned)(h + (t / 3 - 1)) < 128u;
    if (rowok) {
#pragma unroll
      for (int nb = 0; nb < NBL; ++nb) {
#pragma unroll
        for (int kb = 0; kb < KB; ++kb) {
          half8 b = ldfrag(smem + (size_t)((t * KB + kb) * NBL + nb) * 512 + lane * 8);
          acc[0][nb] = mfma16(aq[t % NS][0][kb], b, acc[0][nb]);
          acc[1][nb] = mfma16(aq[t % NS][1][kb], b, acc[1][nb]);
        }
      }
    }
  }

  if (out_fp32) {
    // final output: pixel-major fp32, quad-contiguous 64B runs — direct store
#pragma unroll
    for (int m = 0; m < 2; ++m)
#pragma unroll
      for (int nb = 0; nb < NBL; ++nb) {
        const int ch = nh * NBL * 16 + nb * 16 + l15;
        float bv = bias[ch];
#pragma unroll
        for (int r = 0; r < 4; ++r) {
          float v = fmaxf(acc[m][nb][r] + bv, 0.f);
          size_t px = (size_t)(p0 + m * 16 + (lane >> 4) * 4 + r);
          ((float*)outp)[px * COUT + ch] = v;
        }
      }
  } else {
    // fp16 plane output: chunked epilogue through wave-private LDS scratch
    __syncthreads();                        // weights dead for ALL waves now
    _Float16* T = smem + wid * 1152;        // wave-private 16x72 tile
    const int pxl = lane >> 2, co0 = lane & 3;
#pragma unroll
    for (int m = 0; m < 2; ++m) {
#pragma unroll
      for (int nb = 0; nb < NBL; ++nb) {
        const int chl = nb * 16 + l15;      // local ch within N-half (0..63)
        float bv = bias[nh * NBL * 16 + chl];
#pragma unroll
        for (int r = 0; r < 4; ++r)
          T[((lane >> 4) * 4 + r) * 72 + chl] =
              (_Float16)fmaxf(acc[m][nb][r] + bv, 0.f);
      }
      const size_t pxg = (size_t)(p0 + m * 16 + pxl);
      half8 h0 = ldfrag(T + pxl * 72 + co0 * 8);
      half8 h1 = ldfrag(T + pxl * 72 + (co0 + 4) * 8);
      *(half8*)((_Float16*)outp + (size_t)(nh * 8 + co0) * PLANE + pxg * 8) = h0;
      *(half8*)((_Float16*)outp + (size_t)(nh * 8 + co0 + 4) * PLANE + pxg * 8) = h1;
    }
  }
}

extern "C" void kernel_launch(void* const* d_in, const int* in_sizes, int n_in,
                              void* d_out, int out_size, void* d_ws, size_t ws_size,
                              hipStream_t stream) {
  (void)in_sizes; (void)n_in; (void)out_size; (void)ws_size;
  const float* x   = (const float*)d_in[0];
  const float* Kp  = (const float*)d_in[1];
  const float* Vp  = (const float*)d_in[2];
  const float* Qp  = (const float*)d_in[3];
  const float* f1w = (const float*)d_in[4];
  const float* f1b = (const float*)d_in[5];
  const float* f2w = (const float*)d_in[6];
  const float* f2b = (const float*)d_in[7];
  const float* f3w = (const float*)d_in[8];
  const float* f3b = (const float*)d_in[9];

  // ws (halves): xh 8 planes [0,4194304) | wf [4194304,4423680)
  // | t1 8 planes [4423680,8617984) | t2 16 planes [8617984,17006592)  ~34 MB
  _Float16* xh  = (_Float16*)d_ws;
  _Float16* wf  = xh + 4194304;
  _Float16* t1g = wf + 229376;
  _Float16* t2g = t1g + 4194304;
  float* outp = (float*)d_out;

  (void)hipFuncSetAttribute((const void*)attn_ff1,
      hipFuncAttributeMaxDynamicSharedMemorySize, 157696);
  (void)hipFuncSetAttribute((const void*)conv3x3<2, 4, 128, 3>,
      hipFuncAttributeMaxDynamicSharedMemorySize, 73728);
  (void)hipFuncSetAttribute((const void*)conv3x3<4, 2, 64, 1>,
      hipFuncAttributeMaxDynamicSharedMemorySize, 73728);

  prep<<<2944, 256, 0, stream>>>(x, Kp, Vp, Qp, f1w, f2w, f3w, xh, wf);
  attn_ff1<<<256, 512, 157696, stream>>>(xh, wf, f1b, t1g);
  conv3x3<2, 4, 128, 3><<<512, 512, 73728, stream>>>(t1g, wf + 81920, f2b, t2g, 0);
  conv3x3<4, 2, 64, 1><<<512, 512, 73728, stream>>>(t2g, wf + 155648, f3b, outp, 1);
}

// Round 13
// 136.683 us; speedup vs baseline: 1.3446x; 1.0076x over previous
//
#include <hip/hip_runtime.h>

// B=4, H=W=128, D=64, NH=2, hd=32, 9 taps. All inputs fp32; compute fp16 MFMA.
// R13 = R12 + (a) conv3 K-SPLIT two-pass: kb{0,1} then kb{2,3}, acc persists,
// queue slot shrinks 32->16 VGPRs enabling DEPTH=2 under the lb(512,4) cap;
// (b) attn x-load queue depth 3 -> 4 (5 slots). Rest unchanged: LDS-staged
// weights, octet-plane activations, one-pass online softmax, chunked epilogues.

typedef _Float16 half8 __attribute__((ext_vector_type(8)));
typedef float f32x4 __attribute__((ext_vector_type(4)));

#define PLANE 524288  // 65536 pixels x 8 halves per plane

__device__ __forceinline__ f32x4 mfma16(half8 a, half8 b, f32x4 c) {
  return __builtin_amdgcn_mfma_f32_16x16x32_f16(a, b, c, 0, 0, 0);
}
__device__ __forceinline__ half8 ldfrag(const _Float16* p) { return *(const half8*)p; }
__device__ __forceinline__ half8 zfrag() { half8 z = {}; return z; }

__device__ __forceinline__ void gload_lds16(const _Float16* g, _Float16* l) {
  __builtin_amdgcn_global_load_lds(
      (const __attribute__((address_space(1))) void*)g,
      (__attribute__((address_space(3))) void*)l, 16, 0, 0);
}

// ---------------- prep: x -> fp16 octet planes + weight repack -------------
//   AQ  [mb4][kb2]      @ 0       AK  [t9][cb4][kb2]  @ 4096
//   BV  [t9][kb2][nb4]  @ 40960   B1  [kb2][nb4]      @ 77824
//   BF2 [t9][kb2][nb8]  @ 81920   BF3 [t9][kb4][nb4]  @ 155648  (229376 total)
__global__ __launch_bounds__(256) void prep(
    const float* __restrict__ x, const float* __restrict__ Kp,
    const float* __restrict__ Vp, const float* __restrict__ Qp,
    const float* __restrict__ W1, const float* __restrict__ F2,
    const float* __restrict__ F3, _Float16* __restrict__ xh,
    _Float16* __restrict__ out) {
  if (blockIdx.x < 2048) {
    const int t = threadIdx.x;
    const int px = blockIdx.x * 32 + (t >> 3);
    const int oct = t & 7;
    const float4* s = (const float4*)(x + (size_t)px * 64 + oct * 8);
    float4 a = s[0], b = s[1];
    half8 h = { (_Float16)a.x, (_Float16)a.y, (_Float16)a.z, (_Float16)a.w,
                (_Float16)b.x, (_Float16)b.y, (_Float16)b.z, (_Float16)b.w };
    *(half8*)(xh + (size_t)oct * PLANE + (size_t)px * 8) = h;
    return;
  }
  int e = (blockIdx.x - 2048) * 256 + threadIdx.x;  // 229376 total
  int j = e & 7, l = (e >> 3) & 63, f = e >> 9;
  int l15 = l & 15, q8 = (l >> 4) * 8;
  float v;
  if (f < 8)        { int mb = f >> 1, kb = f & 1;
                      v = Qp[(kb*32 + q8 + j) * 64 + mb*16 + l15]; }
  else if (f < 80)  { int g = f - 8, t = g >> 3, mb = (g >> 1) & 3, kb = g & 1;
                      v = Kp[(kb*32 + q8 + j) * 576 + t*64 + mb*16 + l15]; }
  else if (f < 152) { int g = f - 80, t = g >> 3, kb = (g >> 2) & 1, nb = g & 3;
                      v = Vp[(kb*32 + q8 + j) * 576 + t*64 + nb*16 + l15]; }
  else if (f < 160) { int g = f - 152, kb = g >> 2, nb = g & 3;
                      v = W1[(kb*32 + q8 + j) * 64 + nb*16 + l15]; }
  else if (f < 304) { int g = f - 160, t = g >> 4, kb = (g >> 3) & 1, nb = g & 7;
                      v = F2[(t*64 + kb*32 + q8 + j) * 128 + nb*16 + l15]; }
  else              { int g = f - 304, t = g >> 4, kb = (g >> 2) & 3, nb = g & 3;
                      v = F3[(t*128 + kb*32 + q8 + j) * 64 + nb*16 + l15]; }
  out[e] = (_Float16)v;
}

// ---------------- attention + ff1, one-pass online softmax -----------------
// 512 thr = 8 waves; block = 2 rows; wave = 32 px (m=2). LDS (halves):
// AK[0,36864) BV[36864,73728) B1[73728,77824) dentab(f32) @77824.
// x-tap loads flow through a 5-slot register queue, 4 taps ahead.
__global__ __launch_bounds__(512) void attn_ff1(
    const _Float16* __restrict__ xh, const _Float16* __restrict__ wf,
    const float* __restrict__ f1b, _Float16* __restrict__ t1g) {
  extern __shared__ _Float16 smem[];
  const int lane = threadIdx.x & 63, wid = threadIdx.x >> 6;
  const int l15 = lane & 15, q8 = (lane >> 4) * 8;
  const int row = blockIdx.x * 2 + (wid >> 2);
  const int rw = wid & 3;
  const int p0 = row * 128 + rw * 32;
  const int h = row & 127;
  const int w0 = rw * 32;
  const int oct0 = lane >> 4;               // x0 plane; x1 plane = oct0+4
  float* dent = (float*)(smem + 77824) + wid * 64;

  // stage AK+BV+B1 (152 frags, 19/wave); in flight during qT + prologue
  {
    const _Float16* gw = wf + 4096 + (size_t)(wid * 19) * 512;
    _Float16* lw = smem + wid * 19 * 512;
    for (int i = 0; i < 19; ++i)
      gload_lds16(gw + i * 512 + lane * 8, lw + i * 512);
  }

  // own-x fragments + q^T tiles
  half8 ax0[2], ax1[2];
#pragma unroll
  for (int m = 0; m < 2; ++m) {
    const size_t px = (size_t)(p0 + m * 16 + l15);
    ax0[m] = ldfrag(xh + (size_t)oct0 * PLANE + px * 8);
    ax1[m] = ldfrag(xh + (size_t)(oct0 + 4) * PLANE + px * 8);
  }
  f32x4 qT[2][4];
#pragma unroll
  for (int cb = 0; cb < 4; ++cb) {
    half8 aq0 = ldfrag(wf + (cb * 2 + 0) * 512 + lane * 8);
    half8 aq1 = ldfrag(wf + (cb * 2 + 1) * 512 + lane * 8);
#pragma unroll
    for (int m = 0; m < 2; ++m) {
      f32x4 c = {};
      c = mfma16(aq0, ax0[m], c);
      c = mfma16(aq1, ax1[m], c);
      qT[m][cb] = c;
    }
  }

  auto load_tap = [&](int t, half8 (&x0)[2], half8 (&x1)[2]) {
    const int dh = t / 3 - 1, dw = t % 3 - 1;
    const bool rk = (unsigned)(h + dh) < 128u;
#pragma unroll
    for (int m = 0; m < 2; ++m) {
      const bool cv = rk && ((unsigned)(w0 + m * 16 + l15 + dw) < 128u);
      const size_t px = (size_t)(p0 + m * 16 + l15 + dh * 128 + dw);
      x0[m] = cv ? ldfrag(xh + (size_t)oct0 * PLANE + px * 8) : zfrag();
      x1[m] = cv ? ldfrag(xh + (size_t)(oct0 + 4) * PLANE + px * 8) : zfrag();
    }
  };

  float den0[2] = {0.f, 0.f}, den1[2] = {0.f, 0.f};
  auto score_tap = [&](int t, half8 (&x0)[2], half8 (&x1)[2],
                       float (&e0)[2], float (&e1)[2]) {
    const int dh = t / 3 - 1;
    const bool rowok = (unsigned)(h + dh) < 128u;
    half8 kf[8];
    if (rowok) {
#pragma unroll
      for (int f = 0; f < 8; ++f)
        kf[f] = ldfrag(smem + (t * 8 + f) * 512 + lane * 8);
    }
#pragma unroll
    for (int m = 0; m < 2; ++m) {
      float pa = 0.f, pb = 0.f;
      if (rowok) {
#pragma unroll
        for (int cb = 0; cb < 4; ++cb) {
          f32x4 c = {};
          c = mfma16(kf[cb * 2 + 0], x0[m], c);
          c = mfma16(kf[cb * 2 + 1], x1[m], c);
          float d = qT[m][cb].x * c.x + qT[m][cb].y * c.y
                  + qT[m][cb].z * c.z + qT[m][cb].w * c.w;
          if (cb < 2) pa += d; else pb += d;
        }
        pa += __shfl_xor(pa, 16, 64); pa += __shfl_xor(pa, 32, 64);
        pb += __shfl_xor(pb, 16, 64); pb += __shfl_xor(pb, 32, 64);
      }
      e0[m] = __expf(pa * (1.f / 3.f));
      e1[m] = __expf(pb * (1.f / 3.f));
      den0[m] += e0[m]; den1[m] += e1[m];
    }
  };

  // 5-slot register queue, 4 taps in flight; prologue overlaps staging drain
  half8 q0[5][2], q1[5][2];
  load_tap(0, q0[0], q1[0]);
  load_tap(1, q0[1], q1[1]);
  load_tap(2, q0[2], q1[2]);
  load_tap(3, q0[3], q1[3]);

  __syncthreads();                          // staging complete

  float e0c[2], e1c[2];
  score_tap(0, q0[0], q1[0], e0c, e1c);

  const _Float16* BVl = smem + 36864;
  f32x4 at[2][4];
#pragma unroll
  for (int m = 0; m < 2; ++m)
#pragma unroll
    for (int nb = 0; nb < 4; ++nb) at[m][nb] = f32x4{};

#pragma unroll
  for (int t = 0; t < 9; ++t) {
    if (t + 4 < 9) load_tap(t + 4, q0[(t + 4) % 5], q1[(t + 4) % 5]);
    const bool rowok = (unsigned)(h + (t / 3 - 1)) < 128u;
    if (rowok) {
      half8 vf[8];
#pragma unroll
      for (int f = 0; f < 8; ++f) vf[f] = ldfrag(BVl + (t * 8 + f) * 512 + lane * 8);
#pragma unroll
      for (int m = 0; m < 2; ++m) {
        _Float16 h0 = (_Float16)e0c[m], h1 = (_Float16)e1c[m];
        half8 b0 = {h0, h0, h0, h0, h0, h0, h0, h0};
        half8 b1 = {h1, h1, h1, h1, h1, h1, h1, h1};
        half8 s00 = q0[t % 5][m] * b0, s01 = q1[t % 5][m] * b0;
        half8 s10 = q0[t % 5][m] * b1, s11 = q1[t % 5][m] * b1;
#pragma unroll
        for (int nb = 0; nb < 2; ++nb) {
          at[m][nb]     = mfma16(s00, vf[0 * 4 + nb],     at[m][nb]);
          at[m][nb]     = mfma16(s01, vf[1 * 4 + nb],     at[m][nb]);
          at[m][nb + 2] = mfma16(s10, vf[0 * 4 + nb + 2], at[m][nb + 2]);
          at[m][nb + 2] = mfma16(s11, vf[1 * 4 + nb + 2], at[m][nb + 2]);
        }
      }
    }
    if (t < 8) {
      float e0n[2], e1n[2];
      score_tap(t + 1, q0[(t + 1) % 5], q1[(t + 1) % 5], e0n, e1n);
#pragma unroll
      for (int m = 0; m < 2; ++m) { e0c[m] = e0n[m]; e1c[m] = e1n[m]; }
    }
  }

  // per-pixel 1/den via per-wave LDS table
#pragma unroll
  for (int m = 0; m < 2; ++m) {
    dent[(m * 2 + 0) * 16 + l15] = den0[m];
    dent[(m * 2 + 1) * 16 + l15] = den1[m];
  }
  f32x4 iv[2][2];
#pragma unroll
  for (int m = 0; m < 2; ++m)
#pragma unroll
    for (int hd = 0; hd < 2; ++hd) {
      f32x4 dv = *(const f32x4*)(dent + (m * 2 + hd) * 16 + (lane >> 4) * 4);
      iv[m][hd] = f32x4{1.f / dv.x, 1.f / dv.y, 1.f / dv.z, 1.f / dv.w};
    }

  // -------- ff1: normalize + transpose -> GEMM -> CHUNKED plane store ------
  __syncthreads();                          // done reading AK/BV
  _Float16* myt = smem + wid * 2304;        // wave-private 2x1152
#pragma unroll
  for (int m = 0; m < 2; ++m)
#pragma unroll
    for (int nb = 0; nb < 4; ++nb) {
      const int hd = nb >> 1;
#pragma unroll
      for (int r = 0; r < 4; ++r)
        myt[m * 1152 + ((lane >> 4) * 4 + r) * 72 + nb * 16 + l15] =
            (_Float16)(at[m][nb][r] * iv[m][hd][r]);
    }
  const _Float16* B1l = smem + 73728;
  const int pxl = lane >> 2;                // chunk readback: pixel 0..15
  const int co0 = lane & 3;                 // octs co0 and co0+4
#pragma unroll
  for (int m = 0; m < 2; ++m) {
    _Float16* T = myt + m * 1152;           // input tile; reused as output tile
    half8 aa0 = ldfrag(T + l15 * 72 + q8);
    half8 aa1 = ldfrag(T + l15 * 72 + 32 + q8);
#pragma unroll
    for (int nb = 0; nb < 4; ++nb) {
      f32x4 c = {};
      c = mfma16(aa0, ldfrag(B1l + (0 * 4 + nb) * 512 + lane * 8), c);
      c = mfma16(aa1, ldfrag(B1l + (1 * 4 + nb) * 512 + lane * 8), c);
      float bv = f1b[nb * 16 + l15];
#pragma unroll
      for (int r = 0; r < 4; ++r)           // overwrite tile slot m (input dead)
        T[((lane >> 4) * 4 + r) * 72 + nb * 16 + l15] =
            (_Float16)fmaxf(c[r] + bv, 0.f);
    }
    // readback 16B chunks, contiguous 16B stores (16 lanes/oct -> 256B runs)
    const size_t pxg = (size_t)(p0 + m * 16 + pxl);
    half8 h0 = ldfrag(T + pxl * 72 + co0 * 8);
    half8 h1 = ldfrag(T + pxl * 72 + (co0 + 4) * 8);
    *(half8*)(t1g + (size_t)co0 * PLANE + pxg * 8) = h0;
    *(half8*)(t1g + (size_t)(co0 + 4) * PLANE + pxg * 8) = h1;
  }
}

// ---------------- conv2: 3x3, N-split, octet-plane I/O, DEPTH=3 (R12) ------
template <int KB, int NBL, int COUT, int DEPTH>
__global__ __launch_bounds__(512, 4) void conv3x3(
    const _Float16* __restrict__ in, const _Float16* __restrict__ wfrag,
    const float* __restrict__ bias, void* __restrict__ outp, int out_fp32) {
  extern __shared__ _Float16 smem[];
  constexpr int NS = DEPTH + 1;
  const int lane = threadIdx.x & 63, wid = threadIdx.x >> 6;
  const int l15 = lane & 15;
  const int nh = blockIdx.x & 1;
  const int pairIdx = blockIdx.x >> 1;
  const int row = pairIdx * 2 + (wid >> 2);
  const int rw = wid & 3;
  const int p0 = row * 128 + rw * 32;
  const int h = row & 127;
  const int w0 = rw * 32;
  const int NBF = COUT / 16;
  const int oct0 = lane >> 4;

  {
    for (int s = 0; s < 9; ++s) {
      int f = wid * 9 + s;
      int t = f >> 3, r = f & 7, kb = r / NBL, i = r % NBL;
      const _Float16* g = wfrag + (size_t)((t * KB + kb) * NBF + nh * NBL + i) * 512;
      gload_lds16(g + lane * 8, smem + f * 512);
    }
  }

  f32x4 acc[2][NBL];
#pragma unroll
  for (int m = 0; m < 2; ++m)
#pragma unroll
    for (int nb = 0; nb < NBL; ++nb) acc[m][nb] = f32x4{};

  auto load_conv = [&](int t, half8 (&dst)[2][KB]) {
    const int dh = t / 3 - 1, dw = t % 3 - 1;
    const bool rk = (unsigned)(h + dh) < 128u;
#pragma unroll
    for (int m = 0; m < 2; ++m) {
      const bool cv = rk && ((unsigned)(w0 + m * 16 + l15 + dw) < 128u);
      const size_t px = (size_t)(p0 + m * 16 + l15 + dh * 128 + dw);
#pragma unroll
      for (int kb = 0; kb < KB; ++kb)
        dst[m][kb] = cv ? ldfrag(in + (size_t)(kb * 4 + oct0) * PLANE + px * 8) : zfrag();
    }
  };

  half8 aq[NS][2][KB];
#pragma unroll
  for (int d = 0; d < DEPTH; ++d) load_conv(d, aq[d]);  // overlap staging

  __syncthreads();

#pragma unroll
  for (int t = 0; t < 9; ++t) {
    if (t + DEPTH < 9) load_conv(t + DEPTH, aq[(t + DEPTH) % NS]);
    const bool rowok = (unsigned)(h + (t / 3 - 1)) < 128u;
    if (rowok) {
#pragma unroll
      for (int nb = 0; nb < NBL; ++nb) {
#pragma unroll
        for (int kb = 0; kb < KB; ++kb) {
          half8 b = ldfrag(smem + (size_t)((t * KB + kb) * NBL + nb) * 512 + lane * 8);
          acc[0][nb] = mfma16(aq[t % NS][0][kb], b, acc[0][nb]);
          acc[1][nb] = mfma16(aq[t % NS][1][kb], b, acc[1][nb]);
        }
      }
    }
  }

  if (out_fp32) {
#pragma unroll
    for (int m = 0; m < 2; ++m)
#pragma unroll
      for (int nb = 0; nb < NBL; ++nb) {
        const int ch = nh * NBL * 16 + nb * 16 + l15;
        float bv = bias[ch];
#pragma unroll
        for (int r = 0; r < 4; ++r) {
          float v = fmaxf(acc[m][nb][r] + bv, 0.f);
          size_t px = (size_t)(p0 + m * 16 + (lane >> 4) * 4 + r);
          ((float*)outp)[px * COUT + ch] = v;
        }
      }
  } else {
    // fp16 plane output: chunked epilogue through wave-private LDS scratch
    __syncthreads();                        // weights dead for ALL waves now
    _Float16* T = smem + wid * 1152;        // wave-private 16x72 tile
    const int pxl = lane >> 2, co0 = lane & 3;
#pragma unroll
    for (int m = 0; m < 2; ++m) {
#pragma unroll
      for (int nb = 0; nb < NBL; ++nb) {
        const int chl = nb * 16 + l15;      // local ch within N-half (0..63)
        float bv = bias[nh * NBL * 16 + chl];
#pragma unroll
        for (int r = 0; r < 4; ++r)
          T[((lane >> 4) * 4 + r) * 72 + chl] =
              (_Float16)fmaxf(acc[m][nb][r] + bv, 0.f);
      }
      const size_t pxg = (size_t)(p0 + m * 16 + pxl);
      half8 h0 = ldfrag(T + pxl * 72 + co0 * 8);
      half8 h1 = ldfrag(T + pxl * 72 + (co0 + 4) * 8);
      *(half8*)((_Float16*)outp + (size_t)(nh * 8 + co0) * PLANE + pxg * 8) = h0;
      *(half8*)((_Float16*)outp + (size_t)(nh * 8 + co0 + 4) * PLANE + pxg * 8) = h1;
    }
  }
}

// ---------------- conv3: K-SPLIT two-pass (kb{0,1} then kb{2,3}), DEPTH=2 ---
// Block = 2 rows x 32 out-ch (N-half). Queue slot = 2m x 2kbl frags = 16 VGPR
// -> DEPTH=2 fits the lb(512,4) 128-VGPR cap (~95 est). Acc persists across
// passes; same total A/B traffic as the single-pass version.
__global__ __launch_bounds__(512, 4) void conv3b(
    const _Float16* __restrict__ in, const _Float16* __restrict__ wfrag,
    const float* __restrict__ bias, float* __restrict__ outp) {
  extern __shared__ _Float16 smem[];
  const int lane = threadIdx.x & 63, wid = threadIdx.x >> 6;
  const int l15 = lane & 15;
  const int nh = blockIdx.x & 1;
  const int pairIdx = blockIdx.x >> 1;
  const int row = pairIdx * 2 + (wid >> 2);
  const int rw = wid & 3;
  const int p0 = row * 128 + rw * 32;
  const int h = row & 127;
  const int w0 = rw * 32;
  const int oct0 = lane >> 4;
  const int KB = 4, NBL = 2, NBF = 4, COUT = 64;

  {  // stage this N-half's 72 frags (9/wave), layout f=(t*KB+kb)*NBL+nb
    for (int s = 0; s < 9; ++s) {
      int f = wid * 9 + s;
      int t = f >> 3, r = f & 7, kb = r / NBL, i = r % NBL;
      const _Float16* g = wfrag + (size_t)((t * KB + kb) * NBF + nh * NBL + i) * 512;
      gload_lds16(g + lane * 8, smem + f * 512);
    }
  }

  f32x4 acc[2][2];
#pragma unroll
  for (int m = 0; m < 2; ++m)
#pragma unroll
    for (int nb = 0; nb < 2; ++nb) acc[m][nb] = f32x4{};

#pragma unroll
  for (int p = 0; p < 2; ++p) {
    auto load_half = [&](int t, half8 (&dst)[2][2]) {
      const int dh = t / 3 - 1, dw = t % 3 - 1;
      const bool rk = (unsigned)(h + dh) < 128u;
#pragma unroll
      for (int m = 0; m < 2; ++m) {
        const bool cv = rk && ((unsigned)(w0 + m * 16 + l15 + dw) < 128u);
        const size_t px = (size_t)(p0 + m * 16 + l15 + dh * 128 + dw);
#pragma unroll
        for (int kbl = 0; kbl < 2; ++kbl)
          dst[m][kbl] = cv
              ? ldfrag(in + (size_t)((2 * p + kbl) * 4 + oct0) * PLANE + px * 8)
              : zfrag();
      }
    };

    half8 aq[3][2][2];
    load_half(0, aq[0]);
    load_half(1, aq[1]);
    if (p == 0) __syncthreads();            // staging complete (once)

#pragma unroll
    for (int t = 0; t < 9; ++t) {
      if (t + 2 < 9) load_half(t + 2, aq[(t + 2) % 3]);
      const bool rowok = (unsigned)(h + (t / 3 - 1)) < 128u;
      if (rowok) {
#pragma unroll
        for (int nb = 0; nb < 2; ++nb) {
#pragma unroll
          for (int kbl = 0; kbl < 2; ++kbl) {
            half8 b = ldfrag(smem +
                (size_t)((t * KB + 2 * p + kbl) * NBL + nb) * 512 + lane * 8);
            acc[0][nb] = mfma16(aq[t % 3][0][kbl], b, acc[0][nb]);
            acc[1][nb] = mfma16(aq[t % 3][1][kbl], b, acc[1][nb]);
          }
        }
      }
    }
  }

  // final output: pixel-major fp32, quad-contiguous 64B runs — direct store
#pragma unroll
  for (int m = 0; m < 2; ++m)
#pragma unroll
    for (int nb = 0; nb < 2; ++nb) {
      const int ch = nh * 32 + nb * 16 + l15;
      float bv = bias[ch];
#pragma unroll
      for (int r = 0; r < 4; ++r) {
        float v = fmaxf(acc[m][nb][r] + bv, 0.f);
        size_t px = (size_t)(p0 + m * 16 + (lane >> 4) * 4 + r);
        outp[px * COUT + ch] = v;
      }
    }
}

extern "C" void kernel_launch(void* const* d_in, const int* in_sizes, int n_in,
                              void* d_out, int out_size, void* d_ws, size_t ws_size,
                              hipStream_t stream) {
  (void)in_sizes; (void)n_in; (void)out_size; (void)ws_size;
  const float* x   = (const float*)d_in[0];
  const float* Kp  = (const float*)d_in[1];
  const float* Vp  = (const float*)d_in[2];
  const float* Qp  = (const float*)d_in[3];
  const float* f1w = (const float*)d_in[4];
  const float* f1b = (const float*)d_in[5];
  const float* f2w = (const float*)d_in[6];
  const float* f2b = (const float*)d_in[7];
  const float* f3w = (const float*)d_in[8];
  const float* f3b = (const float*)d_in[9];

  // ws (halves): xh 8 planes [0,4194304) | wf [4194304,4423680)
  // | t1 8 planes [4423680,8617984) | t2 16 planes [8617984,17006592)  ~34 MB
  _Float16* xh  = (_Float16*)d_ws;
  _Float16* wf  = xh + 4194304;
  _Float16* t1g = wf + 229376;
  _Float16* t2g = t1g + 4194304;
  float* outp = (float*)d_out;

  (void)hipFuncSetAttribute((const void*)attn_ff1,
      hipFuncAttributeMaxDynamicSharedMemorySize, 157696);
  (void)hipFuncSetAttribute((const void*)conv3x3<2, 4, 128, 3>,
      hipFuncAttributeMaxDynamicSharedMemorySize, 73728);
  (void)hipFuncSetAttribute((const void*)conv3b,
      hipFuncAttributeMaxDynamicSharedMemorySize, 73728);

  prep<<<2944, 256, 0, stream>>>(x, Kp, Vp, Qp, f1w, f2w, f3w, xh, wf);
  attn_ff1<<<256, 512, 157696, stream>>>(xh, wf, f1b, t1g);
  conv3x3<2, 4, 128, 3><<<512, 512, 73728, stream>>>(t1g, wf + 81920, f2b, t2g, 0);
  conv3b<<<512, 512, 73728, stream>>>(t2g, wf + 155648, f3b, outp);
}